// Round 1
// baseline (643.148 us; speedup 1.0000x reference)
//
#include <hip/hip_runtime.h>

#define KSTATES 64

__device__ __forceinline__ float wave_max64(float v) {
#pragma unroll
  for (int off = 32; off; off >>= 1) v = fmaxf(v, __shfl_xor(v, off, 64));
  return v;
}

__device__ __forceinline__ float wave_sum64(float v) {
#pragma unroll
  for (int off = 32; off; off >>= 1) v += __shfl_xor(v, off, 64);
  return v;
}

__global__ __launch_bounds__(64) void crf_forward_kernel(
    const float* __restrict__ emissions,   // [B, T, K]
    const float* __restrict__ transitions, // [K, K]
    const float* __restrict__ start_trans, // [K]
    const float* __restrict__ end_trans,   // [K]
    const int* __restrict__ labels,        // [B, T]
    const int* __restrict__ sent_len,      // [B]
    float* __restrict__ out,               // scalar
    int T, float inv_B) {
  const int b = blockIdx.x;
  const int j = threadIdx.x;  // state index == lane
  const int sl = sent_len[b];

  __shared__ float Abuf[2][KSTATES];

  // Preload exp(transitions) column j into registers: c[i] = exp(T[i][j])
  float c[KSTATES];
#pragma unroll
  for (int i = 0; i < KSTATES; ++i) c[i] = __expf(transitions[i * KSTATES + j]);

  const float* em = emissions + (size_t)b * T * KSTATES + j;
  const int* lbl = labels + (size_t)b * T;

  // t = 0 init
  float e0 = em[0];
  float alpha0 = start_trans[j] + e0;
  float m0 = wave_max64(alpha0);
  float a = __expf(alpha0 - m0);  // linear-space, normalized
  float C = m0;                   // log offset: alpha_t[j] = C + log(a[j] * r)
  float r = 1.0f;                 // pending (stale) renormalizer

  int lab_prev = lbl[0];
  float gold = start_trans[lab_prev] + __shfl(e0, lab_prev, 64);

  // emission prefetch ring (depth 4)
  const int tmax = T - 1;
  float p0 = em[(size_t)min(1, tmax) * KSTATES];
  float p1 = em[(size_t)min(2, tmax) * KSTATES];
  float p2 = em[(size_t)min(3, tmax) * KSTATES];
  float p3 = em[(size_t)min(4, tmax) * KSTATES];

  for (int t = 1; t < sl; ++t) {
    float emit = p0;
    p0 = p1; p1 = p2; p2 = p3;
    p3 = em[(size_t)min(t + 4, tmax) * KSTATES];

    // off critical path: E folds the emission exp and stale renorm
    float E = __expf(emit) * r;

    float* buf = Abuf[t & 1];
    buf[j] = a;
    __builtin_amdgcn_wave_barrier();

    // dot(a_vec, expT[:,j]) via broadcast float4 LDS reads
    const float4* Av = (const float4*)buf;
    float acc0 = 0.f, acc1 = 0.f, acc2 = 0.f, acc3 = 0.f;
#pragma unroll
    for (int q = 0; q < 16; ++q) {
      float4 v = Av[q];
      acc0 = fmaf(v.x, c[4 * q + 0], acc0);
      acc1 = fmaf(v.y, c[4 * q + 1], acc1);
      acc2 = fmaf(v.z, c[4 * q + 2], acc2);
      acc3 = fmaf(v.w, c[4 * q + 3], acc3);
    }
    float s = (acc0 + acc1) + (acc2 + acc3);
    a = s * E;

    // stale renorm for NEXT step (off critical path)
    float ar = __shfl(a, 0, 64);
    C += __logf(ar);
    r = __builtin_amdgcn_rcpf(ar);

    // gold score (wave-uniform scalar work)
    int lab = lbl[t];
    gold += __shfl(emit, lab, 64) + transitions[lab_prev * KSTATES + lab];
    lab_prev = lab;
  }

  // fwd = logsumexp(alpha + end): alpha[j] = C + log(a[j] * r)
  float v = a * __expf(end_trans[j]);
  float sum = wave_sum64(v);
  float fwd = C + __logf(sum * r);

  gold += end_trans[lab_prev];

  if (j == 0) atomicAdd(out, (fwd - gold) * inv_B);
}

extern "C" void kernel_launch(void* const* d_in, const int* in_sizes, int n_in,
                              void* d_out, int out_size, void* d_ws, size_t ws_size,
                              hipStream_t stream) {
  const float* emissions = (const float*)d_in[0];
  const float* transitions = (const float*)d_in[1];
  const float* start_trans = (const float*)d_in[2];
  const float* end_trans = (const float*)d_in[3];
  const int* labels = (const int*)d_in[4];
  const int* sent_len = (const int*)d_in[5];
  float* out = (float*)d_out;

  const int B = in_sizes[5];
  const int T = in_sizes[4] / B;

  hipMemsetAsync(out, 0, sizeof(float), stream);
  crf_forward_kernel<<<B, KSTATES, 0, stream>>>(
      emissions, transitions, start_trans, end_trans, labels, sent_len, out, T,
      1.0f / (float)B);
}

// Round 2
// 641.714 us; speedup vs baseline: 1.0022x; 1.0022x over previous
//
#include <hip/hip_runtime.h>

#define KSTATES 64
#define PF 8

__device__ __forceinline__ float wave_max64(float v) {
#pragma unroll
  for (int off = 32; off; off >>= 1) v = fmaxf(v, __shfl_xor(v, off, 64));
  return v;
}

__device__ __forceinline__ float wave_sum64(float v) {
#pragma unroll
  for (int off = 32; off; off >>= 1) v += __shfl_xor(v, off, 64);
  return v;
}

__global__ __launch_bounds__(64) void crf_kernel(
    const float* __restrict__ emissions,   // [B, T, K]
    const float* __restrict__ transitions, // [K, K]
    const float* __restrict__ start_trans, // [K]
    const float* __restrict__ end_trans,   // [K]
    const int* __restrict__ labels,        // [B, T]
    const int* __restrict__ sent_len,      // [B]
    float* __restrict__ out,               // scalar
    int T, float inv_B) {
  const int b = blockIdx.x;
  const int j = threadIdx.x;  // state index == lane
  const int sl = sent_len[b];

  __shared__ float Abuf[2][KSTATES];

  // Preload exp(transitions) column j into registers: c[i] = exp(T[i][j])
  float c[KSTATES];
#pragma unroll
  for (int i = 0; i < KSTATES; ++i) c[i] = __expf(transitions[i * KSTATES + j]);

  const float* em = emissions + (size_t)b * T * KSTATES;
  const int* lbl = labels + (size_t)b * T;

  // ---- gold score: lane-parallel over time (independent gathers, fully
  // pipelined; removed from the sequential scan loop entirely) ----
  float g = 0.f;
  for (int t0 = j; t0 < T; t0 += KSTATES) {
    if (t0 < sl) {
      int lab = lbl[t0];
      float v = em[(size_t)t0 * KSTATES + lab];
      if (t0 == 0)
        v += start_trans[lab];
      else
        v += transitions[lbl[t0 - 1] * KSTATES + lab];
      if (t0 == sl - 1) v += end_trans[lab];
      g += v;
    }
  }
  float gold = wave_sum64(g);

  // ---- forward scan (exp-space linear recurrence, stale renorm) ----
  const float* emj = em + j;
  float e0 = emj[0];
  float alpha0 = start_trans[j] + e0;
  float m0 = wave_max64(alpha0);
  float a = __expf(alpha0 - m0);  // linear-space, normalized
  float C = m0;                   // log offset
  float r = 1.0f;                 // one-step-stale renormalizer

  const int tmax = T - 1;
  float ring[PF];
#pragma unroll
  for (int q = 0; q < PF; ++q) ring[q] = emj[(size_t)min(1 + q, tmax) * KSTATES];

  for (int t = 1; t < sl; ++t) {
    float emit = ring[0];
#pragma unroll
    for (int q = 0; q < PF - 1; ++q) ring[q] = ring[q + 1];
    ring[PF - 1] = emj[(size_t)min(t + PF, tmax) * KSTATES];

    // off critical path: fold emission exp and stale renorm
    float E = __expf(emit) * r;

    float* buf = Abuf[t & 1];
    buf[j] = a;
    __builtin_amdgcn_wave_barrier();

    // dot(a_vec, expT[:,j]) via broadcast float4 LDS reads
    const float4* Av = (const float4*)buf;
    float acc0 = 0.f, acc1 = 0.f, acc2 = 0.f, acc3 = 0.f;
#pragma unroll
    for (int q = 0; q < 16; ++q) {
      float4 v = Av[q];
      acc0 = fmaf(v.x, c[4 * q + 0], acc0);
      acc1 = fmaf(v.y, c[4 * q + 1], acc1);
      acc2 = fmaf(v.z, c[4 * q + 2], acc2);
      acc3 = fmaf(v.w, c[4 * q + 3], acc3);
    }
    float s = (acc0 + acc1) + (acc2 + acc3);
    a = s * E;

    // stale renorm for NEXT step (off critical path)
    float ar = __shfl(a, 0, 64);
    C += __logf(ar);
    r = __builtin_amdgcn_rcpf(ar);
  }

  // fwd = logsumexp(alpha + end)
  float v = a * __expf(end_trans[j]);
  float sum = wave_sum64(v);
  float fwd = C + __logf(sum * r);

  if (j == 0) atomicAdd(out, (fwd - gold) * inv_B);
}

extern "C" void kernel_launch(void* const* d_in, const int* in_sizes, int n_in,
                              void* d_out, int out_size, void* d_ws, size_t ws_size,
                              hipStream_t stream) {
  const float* emissions = (const float*)d_in[0];
  const float* transitions = (const float*)d_in[1];
  const float* start_trans = (const float*)d_in[2];
  const float* end_trans = (const float*)d_in[3];
  const int* labels = (const int*)d_in[4];
  const int* sent_len = (const int*)d_in[5];
  float* out = (float*)d_out;

  const int B = in_sizes[5];
  const int T = in_sizes[4] / B;

  hipMemsetAsync(out, 0, sizeof(float), stream);
  crf_kernel<<<B, KSTATES, 0, stream>>>(
      emissions, transitions, start_trans, end_trans, labels, sent_len, out, T,
      1.0f / (float)B);
}